// Round 3
// baseline (76038.257 us; speedup 1.0000x reference)
//
#include <hip/hip_runtime.h>
#include <math.h>

typedef float v4 __attribute__((ext_vector_type(4)));

#define NB 256
#define LATD 128
#define UPS 64
#define H 512
#define V 25
#define TS 500
#define LGS 32
#define NBLK 256
#define NGRP 16
#define GSZ (NBLK / NGRP)

// ---- float offsets in workspace ----
#define OFF_HQ      0                            // hQ[2][128][NB][4]
#define OFF_UCTXQ   (OFF_HQ + 2 * 128 * NB * 4)  // uctxQ[16][NB][4]
#define OFF_EGI     (OFF_UCTXQ + 16 * NB * 4)    // EgiT[1536][32]
#define OFF_WHHQ    (OFF_EGI + 1536 * 32)        // Whh_q[128][1536][4]
#define OFF_WCATQ   (OFF_WHHQ + 128 * 1536 * 4)  // Wcat_q[128][512][4]
#define OFF_WFOLDQ  (OFF_WCATQ + 128 * 512 * 4)  // Wfold_q[16][512][4]
#define OFF_WMQ     (OFF_WFOLDQ + 16 * 512 * 4)  // Wm_q2[128][64][4]
#define OFF_BCAT2   (OFF_WMQ + 128 * 64 * 4)     // bcat2[512]
#define OFF_LGT     (OFF_BCAT2 + 512)            // logitsT[2][32][NB]
#define OFF_BAR     (OFF_LGT + 2 * LGS * NB)     // barrier ints

__device__ __forceinline__ float dot4(v4 a, v4 b) {
    return a.x * b.x + a.y * b.y + a.z * b.z + a.w * b.w;
}

// ---------------- init kernels ----------------

__global__ void k_init_egi(const float* __restrict__ embed, const float* __restrict__ W_ih,
                           const float* __restrict__ b_ih, float* __restrict__ EgiT) {
    int idx = blockIdx.x * 256 + threadIdx.x;
    if (idx >= V * 3 * H) return;
    int v = idx % V, n = idx / V;
    const float* e = embed + (size_t)v * H;
    const float* wr = W_ih + (size_t)n * H;
    float acc = b_ih[n];
    for (int k = 0; k < H; ++k) acc += e[k] * wr[k];
    EgiT[n * 32 + v] = acc;
}

// h0 packed: hQ[(j>>2)*NB*4 + b*4 + (j&3)]
__global__ void k_init_h0(const float* __restrict__ latent, const float* __restrict__ W_hid,
                          const float* __restrict__ b_hid, float* __restrict__ hQ) {
    int b = blockIdx.x, j = threadIdx.x;
    const float* l = latent + (size_t)b * LATD;
    const float* wr = W_hid + (size_t)j * LATD;
    float acc = b_hid[j];
    for (int k = 0; k < LATD; ++k) acc += l[k] * wr[k];
    hQ[((j >> 2) * NB + b) * 4 + (j & 3)] = acc;
}

__global__ void k_pack_whh(const float* __restrict__ W_hh, float* __restrict__ Whh_q) {
    int idx = blockIdx.x * 256 + threadIdx.x;  // (row<1536, k4<128)
    if (idx >= 1536 * 128) return;
    int k4 = idx & 127, row = idx >> 7;
    v4 val = *(const v4*)(W_hh + (size_t)row * H + k4 * 4);
    *(v4*)(Whh_q + ((size_t)k4 * 1536 + row) * 4) = val;
}

__global__ void k_pack_wcat(const float* __restrict__ W_cat, float* __restrict__ Wcat_q) {
    int idx = blockIdx.x * 256 + threadIdx.x;  // (row<512, k4<128)
    if (idx >= 512 * 128) return;
    int k4 = idx & 127, row = idx >> 7;
    v4 val = *(const v4*)(W_cat + (size_t)row * (2 * H) + k4 * 4);
    *(v4*)(Wcat_q + ((size_t)k4 * 512 + row) * 4) = val;
}

// Wfold[j][u] = sum_k W_cat[j][512+k] * W_mem[k][u], written packed [u4][512][4]
__global__ void k_init_fold(const float* __restrict__ W_cat, const float* __restrict__ W_mem,
                            float* __restrict__ Wfold_q) {
    int idx = blockIdx.x * 256 + threadIdx.x;
    if (idx >= H * UPS) return;
    int u = idx & 63, j = idx >> 6;
    float acc = 0.f;
    for (int k = 0; k < H; ++k)
        acc += W_cat[(size_t)j * (2 * H) + H + k] * W_mem[(size_t)k * UPS + u];
    Wfold_q[((u >> 2) * 512 + j) * 4 + (u & 3)] = acc;
}

__global__ void k_init_bcat(const float* __restrict__ W_cat, const float* __restrict__ b_mem,
                            const float* __restrict__ b_cat, float* __restrict__ bcat2) {
    int j = blockIdx.x * 256 + threadIdx.x;
    if (j >= H) return;
    float acc = b_cat[j];
    for (int k = 0; k < H; ++k) acc += W_cat[(size_t)j * (2 * H) + H + k] * b_mem[k];
    bcat2[j] = acc;
}

// Wm_q2[k4][u][e] = W_mem[k4*4+e][u]
__global__ void k_pack_wmem(const float* __restrict__ W_mem, float* __restrict__ Wm_q2) {
    int idx = blockIdx.x * 256 + threadIdx.x;  // (k4<128, u<64)
    if (idx >= 128 * 64) return;
    int u = idx & 63, k4 = idx >> 6;
    v4 val;
    val.x = W_mem[(size_t)(k4 * 4 + 0) * UPS + u];
    val.y = W_mem[(size_t)(k4 * 4 + 1) * UPS + u];
    val.z = W_mem[(size_t)(k4 * 4 + 2) * UPS + u];
    val.w = W_mem[(size_t)(k4 * 4 + 3) * UPS + u];
    *(v4*)(Wm_q2 + ((size_t)k4 * 64 + u) * 4) = val;
}

__global__ void k_init_bar(int* __restrict__ bar) {
    int i = threadIdx.x;
    if (i < NGRP * 32 + 64) bar[i] = 0;
}

// ---------------- grid barrier ----------------

__device__ __forceinline__ void grid_barrier(int* bar, int epoch) {
    __syncthreads();
    if (threadIdx.x == 0) {
        int* gcnt = bar + (blockIdx.x & (NGRP - 1)) * 32;
        int* root = bar + NGRP * 32;
        int* gen  = bar + NGRP * 32 + 32;
        int a = __hip_atomic_fetch_add(gcnt, 1, __ATOMIC_RELEASE, __HIP_MEMORY_SCOPE_AGENT);
        if (a == epoch * GSZ + (GSZ - 1)) {
            int r = __hip_atomic_fetch_add(root, 1, __ATOMIC_ACQ_REL, __HIP_MEMORY_SCOPE_AGENT);
            if (r == epoch * NGRP + (NGRP - 1))
                __hip_atomic_store(gen, epoch + 1, __ATOMIC_RELEASE, __HIP_MEMORY_SCOPE_AGENT);
        }
        while (__hip_atomic_load(gen, __ATOMIC_ACQUIRE, __HIP_MEMORY_SCOPE_AGENT) <= epoch)
            __builtin_amdgcn_s_sleep(1);
    }
    __syncthreads();
}

// ---------------- persistent main kernel ----------------

__global__ __launch_bounds__(512, 4) void k_main(
    const float* __restrict__ up, const float* __restrict__ b_hh,
    const float* __restrict__ W_out, const float* __restrict__ b_out,
    float* __restrict__ out, float* __restrict__ ws)
{
    float* hQ       = ws + OFF_HQ;
    float* uctxQ    = ws + OFF_UCTXQ;
    const float* EgiT    = ws + OFF_EGI;
    const float* Whh_q   = ws + OFF_WHHQ;
    const float* Wcat_q  = ws + OFF_WCATQ;
    const float* Wfold_q = ws + OFF_WFOLDQ;
    const float* Wm_q2   = ws + OFF_WMQ;
    const float* bcat2   = ws + OFF_BCAT2;
    float* lgT      = ws + OFF_LGT;
    int*   bar      = (int*)(ws + OFF_BAR);

    const int tid = threadIdx.x;
    const int bid = blockIdx.x;
    const int lane = tid & 63, w = tid >> 6;
    const int bq = bid & 3, jb = bid >> 2;
    const int jg = lane & 7, bg = lane >> 3;
    const int b = bq * 64 + w * 8 + bg;     // P1/P3 batch index
    const int j = jb * 8 + jg;              // P1/P3 output index

    const v4* wq4  = (const v4*)Whh_q;
    const v4* wc4  = (const v4*)Wcat_q;
    const v4* wf4  = (const v4*)Wfold_q;
    const v4* wm4  = (const v4*)Wm_q2;
    const v4* uq4  = (const v4*)uctxQ;

    __shared__ float s_part[8][64];
    __shared__ __align__(16) float s_hp[64];
    __shared__ float s_ctx[8][64];
    __shared__ float s_mw[8], s_Sw[8];

    int ep = 0;

    for (int t = 0; t < TS; ++t) {
        float* hQc = hQ + (size_t)(t & 1) * (128 * NB * 4);
        float* hQn = hQ + (size_t)((t + 1) & 1) * (128 * NB * 4);
        const float* lgprev = lgT + ((t + 1) & 1) * (LGS * NB);
        float* lgcur = lgT + (t & 1) * (LGS * NB);
        const v4* hc4 = (const v4*)hQc;
        const v4* hn4 = (const v4*)hQn;

        // ================= P1: argmax feedback + GRU =================
        int id = 0;
        if (t > 0) {
            float best = lgprev[0 * NB + b];
            for (int v = 1; v < V; ++v) {
                float x = lgprev[v * NB + b];
                if (x > best) { best = x; id = v; }
            }
        }
        if (jb == 0 && t > 0) {  // write output logits for step t-1 (this quarter)
            for (int i = tid; i < 64 * 32; i += 512) {
                int v = i & 31, bl = i >> 5;
                if (v < V) {
                    int bb = bq * 64 + bl;
                    out[((size_t)bb * V + v) * TS + (t - 1)] = lgprev[v * NB + bb];
                }
            }
        }
        if (jb == 1) {  // bias-init logits accumulator for this step
            for (int i = tid; i < V * 64; i += 512) {
                int v = i >> 6, bl = i & 63;
                lgcur[v * NB + bq * 64 + bl] = b_out[v];
            }
        }
        {
            float ar0 = 0.f, ar1 = 0.f, az0 = 0.f, az1 = 0.f, an0 = 0.f, an1 = 0.f;
#pragma unroll 2
            for (int k4 = 0; k4 < 128; k4 += 2) {
                v4 h0 = hc4[k4 * NB + b];
                v4 h1 = hc4[(k4 + 1) * NB + b];
                v4 r0 = wq4[k4 * 1536 + j];
                v4 z0 = wq4[k4 * 1536 + 512 + j];
                v4 n0 = wq4[k4 * 1536 + 1024 + j];
                v4 r1 = wq4[(k4 + 1) * 1536 + j];
                v4 z1 = wq4[(k4 + 1) * 1536 + 512 + j];
                v4 n1 = wq4[(k4 + 1) * 1536 + 1024 + j];
                ar0 += dot4(h0, r0); az0 += dot4(h0, z0); an0 += dot4(h0, n0);
                ar1 += dot4(h1, r1); az1 += dot4(h1, z1); an1 += dot4(h1, n1);
            }
            float gir = EgiT[(0 * H + j) * 32 + id];
            float giz = EgiT[(1 * H + j) * 32 + id];
            float gin = EgiT[(2 * H + j) * 32 + id];
            float sr = ar0 + ar1 + b_hh[j] + gir;
            float sz = az0 + az1 + b_hh[H + j] + giz;
            float sn = an0 + an1 + b_hh[2 * H + j];
            float r = 1.f / (1.f + __expf(-sr));
            float z = 1.f / (1.f + __expf(-sz));
            float n = tanhf(gin + r * sn);
            int hidx = ((j >> 2) * NB + b) * 4 + (j & 3);
            float hold = hQc[hidx];
            hQn[hidx] = (1.f - z) * n + z * hold;
        }
        grid_barrier(bar, ep++);

        // ================= P2: attention (flash-style, one block per b) =================
        {
            const int b2 = bid;
            // hproj[u] = sum_k h_new[k] * W_mem[k][u]; wave w handles k-chunk w
            {
                float a = 0.f;
#pragma unroll 4
                for (int i = 0; i < 16; ++i) {
                    int k4 = w * 16 + i;
                    v4 hv = hn4[k4 * NB + b2];      // broadcast
                    v4 wv = wm4[k4 * 64 + lane];    // coalesced
                    a += dot4(hv, wv);
                }
                s_part[w][lane] = a;
            }
            __syncthreads();
            if (w == 0) {
                float a = s_part[0][lane];
                for (int i = 1; i < 8; ++i) a += s_part[i][lane];
                s_hp[lane] = a;
            }
            __syncthreads();

            const int u0 = (lane & 7) * 8;
            const int tsub = lane >> 3;
            v4 hpA = *(const v4*)&s_hp[u0];
            v4 hpB = *(const v4*)&s_hp[u0 + 4];
            float m = -1e30f, S = 0.f;
            float cx[8] = {0.f, 0.f, 0.f, 0.f, 0.f, 0.f, 0.f, 0.f};
#pragma unroll
            for (int p = 0; p < 8; ++p) {
                int tt = p * 64 + w * 8 + tsub;
                v4 ua = {0.f, 0.f, 0.f, 0.f}, ub = {0.f, 0.f, 0.f, 0.f};
                float part = 0.f;
                if (tt < TS) {
                    const v4* ur = (const v4*)(up + ((size_t)b2 * TS + tt) * UPS + u0);
                    ua = ur[0];
                    ub = ur[1];
                    part = dot4(ua, hpA) + dot4(ub, hpB);
                }
                part += __shfl_xor(part, 1);
                part += __shfl_xor(part, 2);
                part += __shfl_xor(part, 4);
                float s = (tt < TS) ? part : -1e30f;
                float M = s;
                M = fmaxf(M, __shfl_xor(M, 8));
                M = fmaxf(M, __shfl_xor(M, 16));
                M = fmaxf(M, __shfl_xor(M, 32));
                float mn = fmaxf(m, M);
                float alpha = __expf(m - mn);
                float e = __expf(s - mn);
                float E = e;
                E += __shfl_xor(E, 8); E += __shfl_xor(E, 16); E += __shfl_xor(E, 32);
                S = S * alpha + E;
                m = mn;
#pragma unroll
                for (int i = 0; i < 4; ++i) cx[i] = cx[i] * alpha + e * ua[i];
#pragma unroll
                for (int i = 0; i < 4; ++i) cx[4 + i] = cx[4 + i] * alpha + e * ub[i];
            }
#pragma unroll
            for (int i = 0; i < 8; ++i) {
                cx[i] += __shfl_xor(cx[i], 8);
                cx[i] += __shfl_xor(cx[i], 16);
                cx[i] += __shfl_xor(cx[i], 32);
            }
            if (tsub == 0) {
#pragma unroll
                for (int i = 0; i < 8; ++i) s_ctx[w][u0 + i] = cx[i];
            }
            if (lane == 0) { s_mw[w] = m; s_Sw[w] = S; }
            __syncthreads();
            if (tid < UPS) {
                float M = s_mw[0];
                for (int i = 1; i < 8; ++i) M = fmaxf(M, s_mw[i]);
                float Sg = 0.f, c = 0.f;
                for (int i = 0; i < 8; ++i) {
                    float f = __expf(s_mw[i] - M);
                    Sg += s_Sw[i] * f;
                    c += s_ctx[i][tid] * f;
                }
                uctxQ[((tid >> 2) * NB + b2) * 4 + (tid & 3)] = c / Sg;
            }
        }
        grid_barrier(bar, ep++);

        // ================= P3: concat GEMM + folded logits =================
        {
            float acc0 = 0.f, acc1 = 0.f;
#pragma unroll 2
            for (int k4 = 0; k4 < 128; k4 += 2) {
                v4 h0 = hn4[k4 * NB + b];
                v4 h1 = hn4[(k4 + 1) * NB + b];
                v4 w0 = wc4[k4 * 512 + j];
                v4 w1 = wc4[(k4 + 1) * 512 + j];
                acc0 += dot4(h0, w0);
                acc1 += dot4(h1, w1);
            }
#pragma unroll
            for (int u4 = 0; u4 < 16; u4 += 2) {
                v4 u0v = uq4[u4 * NB + b];
                v4 u1v = uq4[(u4 + 1) * NB + b];
                v4 w0 = wf4[u4 * 512 + j];
                v4 w1 = wf4[(u4 + 1) * 512 + j];
                acc0 += dot4(u0v, w0);
                acc1 += dot4(u1v, w1);
            }
            float c = tanhf(acc0 + acc1 + bcat2[j]);
            // logits: reduce over jg within wave, atomically add per (v, b)
            for (int v = 0; v < V; ++v) {
                float p = c * W_out[(size_t)v * H + j];  // [V][H] layout is what we need
                p += __shfl_xor(p, 1);
                p += __shfl_xor(p, 2);
                p += __shfl_xor(p, 4);
                if (jg == 0) atomicAdd(&lgcur[v * NB + b], p);
            }
        }
        grid_barrier(bar, ep++);
    }

    // final output write for t = TS-1
    if (jb == 0) {
        const float* lgfin = lgT + ((TS - 1) & 1) * (LGS * NB);
        for (int i = tid; i < 64 * 32; i += 512) {
            int v = i & 31, bl = i >> 5;
            if (v < V) {
                int bb = bq * 64 + bl;
                out[((size_t)bb * V + v) * TS + (TS - 1)] = lgfin[v * NB + bb];
            }
        }
    }
}

// ---------------- launcher ----------------

extern "C" void kernel_launch(void* const* d_in, const int* in_sizes, int n_in,
                              void* d_out, int out_size, void* d_ws, size_t ws_size,
                              hipStream_t stream) {
    const float* latent = (const float*)d_in[0];
    const float* up     = (const float*)d_in[1];
    const float* embed  = (const float*)d_in[2];
    const float* W_hid  = (const float*)d_in[3];
    const float* b_hid  = (const float*)d_in[4];
    const float* W_ih   = (const float*)d_in[5];
    const float* b_ih   = (const float*)d_in[6];
    const float* W_hh   = (const float*)d_in[7];
    const float* b_hh   = (const float*)d_in[8];
    const float* W_mem  = (const float*)d_in[9];
    const float* b_mem  = (const float*)d_in[10];
    const float* W_cat  = (const float*)d_in[11];
    const float* b_cat  = (const float*)d_in[12];
    const float* W_out  = (const float*)d_in[13];
    const float* b_out  = (const float*)d_in[14];
    float* out = (float*)d_out;
    float* ws = (float*)d_ws;

    k_init_egi<<<(V * 3 * H + 255) / 256, 256, 0, stream>>>(embed, W_ih, b_ih, ws + OFF_EGI);
    k_init_h0<<<NB, H, 0, stream>>>(latent, W_hid, b_hid, ws + OFF_HQ);
    k_pack_whh<<<(1536 * 128 + 255) / 256, 256, 0, stream>>>(W_hh, ws + OFF_WHHQ);
    k_pack_wcat<<<(512 * 128 + 255) / 256, 256, 0, stream>>>(W_cat, ws + OFF_WCATQ);
    k_init_fold<<<(H * UPS + 255) / 256, 256, 0, stream>>>(W_cat, W_mem, ws + OFF_WFOLDQ);
    k_init_bcat<<<(H + 255) / 256, 256, 0, stream>>>(W_cat, b_mem, b_cat, ws + OFF_BCAT2);
    k_pack_wmem<<<(128 * 64 + 255) / 256, 256, 0, stream>>>(W_mem, ws + OFF_WMQ);
    k_init_bar<<<1, 1024, 0, stream>>>((int*)(ws + OFF_BAR));

    k_main<<<NBLK, 512, 0, stream>>>(up, b_hh, W_out, b_out, out, ws);
}